// Round 1
// baseline (196.049 us; speedup 1.0000x reference)
//
#include <hip/hip_runtime.h>
#include <cstdint>

// ViT patch embedding, fused:
//   prep_small: W fp32 -> bf16 Wb in ws; cls rows -> out  (tiny)
//   vit_gemm_fused: patchify+bf16-convert fused into the A-staging of the
//       register-pipelined bf16 GEMM (global fp32 image -> VGPR cvt ->
//       ds_write). Single LDS buffer, XOR-swizzled (0 bank conflicts,
//       verified earlier), XCD-swizzled grid so the 6 n-blocks sharing an
//       A image-slice (393 KB/group, L2-resident) co-locate on one XCD.
// This removes the prep_patch kernel entirely: -77 MB fp32 read, -38.5 MB
// bf16 write, -32 MB re-read, -1 launch. Conversion is bit-identical
// (same bf16rne on same elements) so absmax is unchanged.

#define PGRID 14
#define PSZ   16
#define CHN   3
#define IMGW  224
#define KDIM  768
#define NDIM  768
#define NPATCH 196

typedef short bf16x8 __attribute__((ext_vector_type(8)));
typedef float f32x4  __attribute__((ext_vector_type(4)));

__device__ __forceinline__ short bf16rne(float f) {
    uint32_t u = __builtin_bit_cast(uint32_t, f);
    u += 0x7FFFu + ((u >> 16) & 1u);
    return (short)(u >> 16);
}

__device__ __forceinline__ bf16x8 cvt8(float4 v0, float4 v1) {
    bf16x8 s;
    s[0] = bf16rne(v0.x); s[1] = bf16rne(v0.y); s[2] = bf16rne(v0.z); s[3] = bf16rne(v0.w);
    s[4] = bf16rne(v1.x); s[5] = bf16rne(v1.y); s[6] = bf16rne(v1.z); s[7] = bf16rne(v1.w);
    return s;
}

// patchified A element block: row-base arowb (k-independent), k = chunk start.
// k -> (c, ph, pw): c = k>>8, ph = (k>>4)&15, pw = k&15 (pw in {0,8}).
// 8 consecutive k are 8 contiguous floats in the image row (16B-aligned x2).
__device__ __forceinline__ bf16x8 loadA_patch(
    const float* __restrict__ img, long arowb, int k)
{
    int c  = k >> 8;
    int ph = (k >> 4) & 15;
    int pw = k & 15;
    const float* src = img + arowb + (c * IMGW + ph) * IMGW + pw;
    float4 v0 = *(const float4*)src;
    float4 v1 = *(const float4*)(src + 4);
    return cvt8(v0, v1);
}

// ---------------- prep: W convert + cls fill ----------------
__global__ __launch_bounds__(256) void prep_small(
    const float* __restrict__ Wl, const float* __restrict__ cls,
    short* __restrict__ Wb, float* __restrict__ out, int n_img)
{
    int t = blockIdx.x * 256 + threadIdx.x;
    const int WCH = KDIM * NDIM / 8;   // 73728
    if (t < WCH) {
        float4 v0 = *(const float4*)(Wl + (long)t * 8);
        float4 v1 = *(const float4*)(Wl + (long)t * 8 + 4);
        *(bf16x8*)(Wb + (long)t * 8) = cvt8(v0, v1);
    } else {
        int u = t - WCH;
        if (u < n_img * 96) {
            int im = u / 96;
            int k8 = u - im * 96;
            float4 v0 = *(const float4*)(cls + k8 * 8);
            float4 v1 = *(const float4*)(cls + k8 * 8 + 4);
            float* dst = out + (long)im * 197 * NDIM + k8 * 8;
            *(float4*)dst = v0;
            *(float4*)(dst + 4) = v1;
        }
    }
}

// ---------------- fused GEMM: patchify(img) @ Wb^T + bias ----------------
__global__ __launch_bounds__(256) void vit_gemm_fused(
    const float* __restrict__ img, const short* __restrict__ B,
    const float* __restrict__ bias, float* __restrict__ out,
    int M, int mgroups)
{
    // XCD-aware decode: 6 n-blocks of one m-group land on the same XCD
    const int bid = blockIdx.x;
    const int xcd = bid & 7;
    const int s   = bid >> 3;
    const int gq  = s / 6;
    const int j   = s - gq * 6;
    const int g   = gq * 8 + xcd;          // m-group
    if (g >= mgroups) return;
    const int m0 = g * 128;
    const int n0 = j * 128;

    __shared__ short As[128 * 64];   // 16 KB, XOR-swizzled: (row, k16) at row*64 + ((k16^(row&7))*8)
    __shared__ short Bs[128 * 64];

    const int tid = threadIdx.x;
    const int wave = tid >> 6;
    const int lane = tid & 63;

    // staging coords: slot b = jj*256 + tid; phys LDS offset = b*8 shorts;
    // logical row = jj*32 + (tid>>3); logical chunk = (tid&7) ^ (row&7)
    const int srow = tid >> 3;
    const int sk   = (tid & 7) ^ (srow & 7);
    const int kbase = sk * 8;              // this thread's k-offset inside the 64-slice
    const long bbase = (long)(n0 + srow) * KDIM + kbase;

    // per-staged-row patchify base address (k-independent). Rows clamped to
    // M-1 for the (generic-n) padded tail; out-write guards gm < M.
    long arow[4];
    #pragma unroll
    for (int jj = 0; jj < 4; ++jj) {
        int m  = m0 + srow + jj * 32;
        int mm = (m < M) ? m : (M - 1);
        int im = mm / NPATCH;
        int p  = mm - im * NPATCH;
        int Pi = p / PGRID;
        int Pj = p - Pi * PGRID;
        arow[jj] = ((long)(im * CHN) * IMGW + Pi * PSZ) * IMGW + Pj * PSZ;
    }

    // compute coords
    const int wm = (wave & 1) * 64;
    const int wn = (wave >> 1) * 64;
    const int wq = lane >> 4;
    const int lr = lane & 15;
    const int blk0 = ((wq)     ^ (lr & 7)) * 8;
    const int blk1 = ((wq + 4) ^ (lr & 7)) * 8;

    f32x4 acc[4][4] = {};
    bf16x8 ra[4], rb[4];

    // prologue: load tile 0 into registers (A straight from the image)
    #pragma unroll
    for (int jj = 0; jj < 4; ++jj) {
        ra[jj] = loadA_patch(img, arow[jj], kbase);
        rb[jj] = *(const bf16x8*)(B + bbase + (long)jj * 32 * KDIM);
    }

    for (int kk = 0; kk < KDIM; kk += 64) {
        // spill current regs to LDS (conflict-free: consecutive tid -> consecutive 16B)
        #pragma unroll
        for (int jj = 0; jj < 4; ++jj) {
            *(bf16x8*)(&As[(jj * 256 + tid) * 8]) = ra[jj];
            *(bf16x8*)(&Bs[(jj * 256 + tid) * 8]) = rb[jj];
        }
        __syncthreads();   // lgkm only — no global_load_lds => no vmcnt(0) drain

        // issue next tile's global loads; latency hides behind MFMA phase
        if (kk + 64 < KDIM) {
            #pragma unroll
            for (int jj = 0; jj < 4; ++jj) {
                ra[jj] = loadA_patch(img, arow[jj], kk + 64 + kbase);
                rb[jj] = *(const bf16x8*)(B + bbase + (long)jj * 32 * KDIM + kk + 64);
            }
        }

        #pragma unroll
        for (int ks = 0; ks < 2; ++ks) {
            const int blk = ks ? blk1 : blk0;
            bf16x8 a[4], b[4];
            #pragma unroll
            for (int i = 0; i < 4; ++i)
                a[i] = *(const bf16x8*)(&As[(wm + i * 16 + lr) * 64 + blk]);
            #pragma unroll
            for (int i = 0; i < 4; ++i)
                b[i] = *(const bf16x8*)(&Bs[(wn + i * 16 + lr) * 64 + blk]);
            #pragma unroll
            for (int i = 0; i < 4; ++i)
                #pragma unroll
                for (int jm = 0; jm < 4; ++jm)
                    acc[i][jm] = __builtin_amdgcn_mfma_f32_16x16x32_bf16(a[i], b[jm], acc[i][jm], 0, 0, 0);
        }
        __syncthreads();   // reads of this tile done before next ds_write
    }

    float bv[4];
    #pragma unroll
    for (int jm = 0; jm < 4; ++jm) bv[jm] = bias[n0 + wn + jm * 16 + lr];

    #pragma unroll
    for (int i = 0; i < 4; ++i) {
        #pragma unroll
        for (int r = 0; r < 4; ++r) {
            int gm = m0 + wm + i * 16 + wq * 4 + r;
            if (gm < M) {
                int im = gm / NPATCH;
                int p  = gm - im * NPATCH;
                long orow = ((long)im * 197 + 1 + p) * (long)NDIM;
                #pragma unroll
                for (int jm = 0; jm < 4; ++jm)
                    out[orow + n0 + wn + jm * 16 + lr] = acc[i][jm][r] + bv[jm];
            }
        }
    }
}

// ---------------- fallback (round-1 fused kernel, no ws needed) ----------------
#define LDSTR 40
__global__ __launch_bounds__(256) void vit_gemm_fb(
    const float* __restrict__ img, const float* __restrict__ Wl,
    const float* __restrict__ bias, float* __restrict__ out, int n_img)
{
    const int M = n_img * NPATCH;
    __shared__ short As[128 * LDSTR];
    __shared__ short Bs[128 * LDSTR];
    const int tid = threadIdx.x;
    const int m0 = blockIdx.y * 128;
    const int n0 = blockIdx.x * 128;
    const int col4  = tid & 7;
    const int rbase = tid >> 3;
    long arow[4];
    for (int rr = 0; rr < 4; ++rr) {
        int m = m0 + rbase + rr * 32;
        int mm = (m < M) ? m : (M - 1);
        int im = mm / NPATCH;
        int p  = mm % NPATCH;
        int Pi = p / PGRID;
        int Pj = p % PGRID;
        arow[rr] = ((long)(im * CHN) * IMGW + Pi * PSZ) * IMGW + Pj * PSZ;
    }
    const int lane = tid & 63;
    const int wave = tid >> 6;
    const int wm = (wave & 1) * 64;
    const int wn = (wave >> 1) * 64;
    const int wq = lane >> 4;
    const int lr = lane & 15;
    f32x4 acc[4][4] = {};
    for (int k0 = 0; k0 < KDIM; k0 += 32) {
        {
            int k  = k0 + col4 * 4;
            int c  = k >> 8;
            int ph = (k >> 4) & 15;
            int pw = k & 15;
            long koff = (long)(c * IMGW + ph) * IMGW + pw;
            #pragma unroll
            for (int rr = 0; rr < 4; ++rr) {
                const float4 v = *(const float4*)(img + arow[rr] + koff);
                int row = rbase + rr * 32;
                short4 s;
                s.x = bf16rne(v.x); s.y = bf16rne(v.y);
                s.z = bf16rne(v.z); s.w = bf16rne(v.w);
                *(short4*)(&As[row * LDSTR + col4 * 4]) = s;
            }
        }
        {
            int k = k0 + col4 * 4;
            #pragma unroll
            for (int rr = 0; rr < 4; ++rr) {
                int nrow = rbase + rr * 32;
                const float4 v = *(const float4*)(Wl + (long)(n0 + nrow) * KDIM + k);
                short4 s;
                s.x = bf16rne(v.x); s.y = bf16rne(v.y);
                s.z = bf16rne(v.z); s.w = bf16rne(v.w);
                *(short4*)(&Bs[nrow * LDSTR + col4 * 4]) = s;
            }
        }
        __syncthreads();
        bf16x8 a[4], b[4];
        #pragma unroll
        for (int i = 0; i < 4; ++i)
            a[i] = *(const bf16x8*)(&As[(wm + i * 16 + lr) * LDSTR + wq * 8]);
        #pragma unroll
        for (int i = 0; i < 4; ++i)
            b[i] = *(const bf16x8*)(&Bs[(wn + i * 16 + lr) * LDSTR + wq * 8]);
        #pragma unroll
        for (int i = 0; i < 4; ++i)
            #pragma unroll
            for (int j = 0; j < 4; ++j)
                acc[i][j] = __builtin_amdgcn_mfma_f32_16x16x32_bf16(a[i], b[j], acc[i][j], 0, 0, 0);
        __syncthreads();
    }
    float bv[4];
    #pragma unroll
    for (int j = 0; j < 4; ++j) bv[j] = bias[n0 + wn + j * 16 + lr];
    #pragma unroll
    for (int i = 0; i < 4; ++i) {
        #pragma unroll
        for (int r = 0; r < 4; ++r) {
            int gm = m0 + wm + i * 16 + wq * 4 + r;
            if (gm < M) {
                int im = gm / NPATCH;
                int p  = gm % NPATCH;
                long orow = ((long)im * 197 + 1 + p) * (long)NDIM;
                #pragma unroll
                for (int j = 0; j < 4; ++j)
                    out[orow + n0 + wn + j * 16 + lr] = acc[i][j][r] + bv[j];
            }
        }
    }
}

__global__ __launch_bounds__(256) void cls_fill(
    const float* __restrict__ cls, float* __restrict__ out, int n_img)
{
    int i = blockIdx.x * 256 + threadIdx.x;
    if (i < n_img * NDIM) {
        int im = i / NDIM;
        int n  = i - im * NDIM;
        out[(long)im * 197 * NDIM + n] = cls[n];
    }
}

extern "C" void kernel_launch(void* const* d_in, const int* in_sizes, int n_in,
                              void* d_out, int out_size, void* d_ws, size_t ws_size,
                              hipStream_t stream) {
    const float* img  = (const float*)d_in[0];
    const float* Wl   = (const float*)d_in[1];
    const float* bias = (const float*)d_in[2];
    const float* cls  = (const float*)d_in[3];
    float* out = (float*)d_out;

    int n_img = in_sizes[0] / (CHN * IMGW * IMGW);
    int M = n_img * NPATCH;
    int mgroups = (M + 127) / 128;

    size_t need = (size_t)KDIM * NDIM * sizeof(short);
    if (ws_size >= need) {
        short* Wb = (short*)d_ws;

        int small_total = KDIM * NDIM / 8 + n_img * 96;
        prep_small<<<(small_total + 255) / 256, 256, 0, stream>>>(Wl, cls, Wb, out, n_img);

        // XCD-swizzled 1-D grid: pad m-groups to multiple of 8
        int gpad = (mgroups + 7) & ~7;
        int nblocks = gpad * 6;
        vit_gemm_fused<<<nblocks, 256, 0, stream>>>(img, Wb, bias, out, M, mgroups);
    } else {
        dim3 grid(NDIM / 128, mgroups);
        vit_gemm_fb<<<grid, 256, 0, stream>>>(img, Wl, bias, out, n_img);
        int cls_elems = n_img * NDIM;
        cls_fill<<<(cls_elems + 255) / 256, 256, 0, stream>>>(cls, out, n_img);
    }
}

// Round 2
// 179.100 us; speedup vs baseline: 1.0946x; 1.0946x over previous
//
#include <hip/hip_runtime.h>
#include <cstdint>

// ViT patch embedding, two-stage (fusion reverted — R1 post-mortem: fused
// patchify put scattered fp32 loads + ~130 cvt VALU insts on the GEMM's
// barrier-to-barrier critical path and converted A 6x redundantly; GEMM
// went 52.8 -> 95.7 us. Two-stage with a faster prep wins.)
//
//   prep_all:  ONE kernel, image-linear iteration (perfectly coalesced
//              contiguous reads, vs old prep_patch's 64B-segment strided
//              reads) that patchifies+converts images -> bf16 A in ws,
//              converts W -> bf16 Wb in ws, and fills cls rows of out.
//   vit_gemm3: UNCHANGED from the verified 52.8 us round-0 kernel.
//              bf16 GEMM, register-pipelined staging, single XOR-swizzled
//              LDS buffer (0 bank conflicts), XCD-swizzled grid.

#define PGRID 14
#define PSZ   16
#define CHN   3
#define IMGW  224
#define KDIM  768
#define NDIM  768
#define NPATCH 196

typedef short bf16x8 __attribute__((ext_vector_type(8)));
typedef short short8v __attribute__((ext_vector_type(8)));
typedef float f32x4  __attribute__((ext_vector_type(4)));

__device__ __forceinline__ short bf16rne(float f) {
    uint32_t u = __builtin_bit_cast(uint32_t, f);
    u += 0x7FFFu + ((u >> 16) & 1u);
    return (short)(u >> 16);
}

__device__ __forceinline__ short8v cvt8(float4 v0, float4 v1) {
    short8v s;
    s[0] = bf16rne(v0.x); s[1] = bf16rne(v0.y); s[2] = bf16rne(v0.z); s[3] = bf16rne(v0.w);
    s[4] = bf16rne(v1.x); s[5] = bf16rne(v1.y); s[6] = bf16rne(v1.z); s[7] = bf16rne(v1.w);
    return s;
}

// ---------------- prep: patchify + W convert + cls fill, image-linear ----------------
// Work decomposition in 8-float granules:
//   [0, IMG8)          : image -> A   (reads fully contiguous, 32B/thread)
//   [IMG8, +W8)        : W fp32 -> bf16 Wb (contiguous both sides)
//   [IMG8+W8, +cls8)   : cls row -> out rows (fp32 copy)
// An 8-float run starting at a multiple of 8 never crosses a patch
// boundary (8 | 16 | 224), so each thread writes ONE short8 to A.
__global__ __launch_bounds__(256) void prep_all(
    const float* __restrict__ img, const float* __restrict__ Wl,
    const float* __restrict__ cls, short* __restrict__ A,
    short* __restrict__ Wb, float* __restrict__ out, int n_img)
{
    const int IMG8 = n_img * (CHN * IMGW * IMGW / 8);   // n*18816
    const int W8   = KDIM * NDIM / 8;                   // 73728
    int t = blockIdx.x * 256 + threadIdx.x;

    if (t < IMG8) {
        // image-linear: t*8 = ((im*3 + c)*224 + h)*224 + w
        int w8    = t % (IMGW / 8);        // 0..27
        int rest  = t / (IMGW / 8);
        int h     = rest % IMGW;           // global row
        int rest2 = rest / IMGW;
        int c     = rest2 % CHN;
        int im    = rest2 / CHN;

        float4 v0 = *(const float4*)(img + (long)t * 8);
        float4 v1 = *(const float4*)(img + (long)t * 8 + 4);

        int Pi = h >> 4;
        int ph = h & 15;
        int Pj = w8 >> 1;
        int pw = (w8 & 1) * 8;
        int m  = im * NPATCH + Pi * PGRID + Pj;
        int k  = (c << 8) + (ph << 4) + pw;
        *(short8v*)(A + (long)m * KDIM + k) = cvt8(v0, v1);
    } else if (t < IMG8 + W8) {
        int u = t - IMG8;
        float4 v0 = *(const float4*)(Wl + (long)u * 8);
        float4 v1 = *(const float4*)(Wl + (long)u * 8 + 4);
        *(short8v*)(Wb + (long)u * 8) = cvt8(v0, v1);
    } else {
        int u = t - IMG8 - W8;
        if (u < n_img * (NDIM / 8)) {
            int im = u / (NDIM / 8);
            int k8 = u - im * (NDIM / 8);
            float4 v0 = *(const float4*)(cls + k8 * 8);
            float4 v1 = *(const float4*)(cls + k8 * 8 + 4);
            float* dst = out + (long)im * 197 * NDIM + k8 * 8;
            *(float4*)dst = v0;
            *(float4*)(dst + 4) = v1;
        }
    }
}

// ---------------- main GEMM: bf16 A[M][768] @ Wb[768][768]^T + bias ----------------
// UNCHANGED from round-0 (verified 52.8 us, 0 bank conflicts).
__global__ __launch_bounds__(256) void vit_gemm3(
    const short* __restrict__ A, const short* __restrict__ B,
    const float* __restrict__ bias, float* __restrict__ out,
    int M, int mgroups)
{
    // XCD-aware decode: 6 n-blocks of one m-group land on the same XCD
    const int bid = blockIdx.x;
    const int xcd = bid & 7;
    const int s   = bid >> 3;
    const int gq  = s / 6;
    const int j   = s - gq * 6;
    const int g   = gq * 8 + xcd;          // m-group
    if (g >= mgroups) return;
    const int m0 = g * 128;
    const int n0 = j * 128;

    __shared__ short As[128 * 64];   // 16 KB, XOR-swizzled: (row, k16) at row*64 + ((k16^(row&7))*8)
    __shared__ short Bs[128 * 64];

    const int tid = threadIdx.x;
    const int wave = tid >> 6;
    const int lane = tid & 63;

    // staging coords: slot b = jj*256 + tid; phys LDS offset = b*8 shorts;
    // logical row = jj*32 + (tid>>3); logical chunk = (tid&7) ^ (row&7)
    const int srow = tid >> 3;
    const int sk   = (tid & 7) ^ (srow & 7);
    const long abase = (long)(m0 + srow) * KDIM + sk * 8;
    const long bbase = (long)(n0 + srow) * KDIM + sk * 8;

    // compute coords
    const int wm = (wave & 1) * 64;
    const int wn = (wave >> 1) * 64;
    const int wq = lane >> 4;
    const int lr = lane & 15;
    const int blk0 = ((wq)     ^ (lr & 7)) * 8;
    const int blk1 = ((wq + 4) ^ (lr & 7)) * 8;

    f32x4 acc[4][4] = {};
    bf16x8 ra[4], rb[4];

    // prologue: load tile 0 into registers
    #pragma unroll
    for (int jj = 0; jj < 4; ++jj) {
        ra[jj] = *(const bf16x8*)(A + abase + (long)jj * 32 * KDIM);
        rb[jj] = *(const bf16x8*)(B + bbase + (long)jj * 32 * KDIM);
    }

    for (int kk = 0; kk < KDIM; kk += 64) {
        // spill current regs to LDS (conflict-free: consecutive tid -> consecutive 16B)
        #pragma unroll
        for (int jj = 0; jj < 4; ++jj) {
            *(bf16x8*)(&As[(jj * 256 + tid) * 8]) = ra[jj];
            *(bf16x8*)(&Bs[(jj * 256 + tid) * 8]) = rb[jj];
        }
        __syncthreads();   // lgkm only — no global_load_lds => no vmcnt(0) drain

        // issue next tile's global loads; latency hides behind MFMA phase
        if (kk + 64 < KDIM) {
            #pragma unroll
            for (int jj = 0; jj < 4; ++jj) {
                ra[jj] = *(const bf16x8*)(A + abase + (long)jj * 32 * KDIM + kk + 64);
                rb[jj] = *(const bf16x8*)(B + bbase + (long)jj * 32 * KDIM + kk + 64);
            }
        }

        #pragma unroll
        for (int ks = 0; ks < 2; ++ks) {
            const int blk = ks ? blk1 : blk0;
            bf16x8 a[4], b[4];
            #pragma unroll
            for (int i = 0; i < 4; ++i)
                a[i] = *(const bf16x8*)(&As[(wm + i * 16 + lr) * 64 + blk]);
            #pragma unroll
            for (int i = 0; i < 4; ++i)
                b[i] = *(const bf16x8*)(&Bs[(wn + i * 16 + lr) * 64 + blk]);
            #pragma unroll
            for (int i = 0; i < 4; ++i)
                #pragma unroll
                for (int jm = 0; jm < 4; ++jm)
                    acc[i][jm] = __builtin_amdgcn_mfma_f32_16x16x32_bf16(a[i], b[jm], acc[i][jm], 0, 0, 0);
        }
        __syncthreads();   // reads of this tile done before next ds_write
    }

    float bv[4];
    #pragma unroll
    for (int jm = 0; jm < 4; ++jm) bv[jm] = bias[n0 + wn + jm * 16 + lr];

    #pragma unroll
    for (int i = 0; i < 4; ++i) {
        #pragma unroll
        for (int r = 0; r < 4; ++r) {
            int gm = m0 + wm + i * 16 + wq * 4 + r;
            if (gm < M) {
                int im = gm / NPATCH;
                int p  = gm - im * NPATCH;
                long orow = ((long)im * 197 + 1 + p) * (long)NDIM;
                #pragma unroll
                for (int jm = 0; jm < 4; ++jm)
                    out[orow + n0 + wn + jm * 16 + lr] = acc[i][jm][r] + bv[jm];
            }
        }
    }
}

// ---------------- fallback (round-1 fused kernel, no ws needed) ----------------
#define LDSTR 40
__global__ __launch_bounds__(256) void vit_gemm_fb(
    const float* __restrict__ img, const float* __restrict__ Wl,
    const float* __restrict__ bias, float* __restrict__ out, int n_img)
{
    const int M = n_img * NPATCH;
    __shared__ short As[128 * LDSTR];
    __shared__ short Bs[128 * LDSTR];
    const int tid = threadIdx.x;
    const int m0 = blockIdx.y * 128;
    const int n0 = blockIdx.x * 128;
    const int col4  = tid & 7;
    const int rbase = tid >> 3;
    long arow[4];
    for (int rr = 0; rr < 4; ++rr) {
        int m = m0 + rbase + rr * 32;
        int mm = (m < M) ? m : (M - 1);
        int im = mm / NPATCH;
        int p  = mm % NPATCH;
        int Pi = p / PGRID;
        int Pj = p % PGRID;
        arow[rr] = ((long)(im * CHN) * IMGW + Pi * PSZ) * IMGW + Pj * PSZ;
    }
    const int lane = tid & 63;
    const int wave = tid >> 6;
    const int wm = (wave & 1) * 64;
    const int wn = (wave >> 1) * 64;
    const int wq = lane >> 4;
    const int lr = lane & 15;
    f32x4 acc[4][4] = {};
    for (int k0 = 0; k0 < KDIM; k0 += 32) {
        {
            int k  = k0 + col4 * 4;
            int c  = k >> 8;
            int ph = (k >> 4) & 15;
            int pw = k & 15;
            long koff = (long)(c * IMGW + ph) * IMGW + pw;
            #pragma unroll
            for (int rr = 0; rr < 4; ++rr) {
                const float4 v = *(const float4*)(img + arow[rr] + koff);
                int row = rbase + rr * 32;
                short4 s;
                s.x = bf16rne(v.x); s.y = bf16rne(v.y);
                s.z = bf16rne(v.z); s.w = bf16rne(v.w);
                *(short4*)(&As[row * LDSTR + col4 * 4]) = s;
            }
        }
        {
            int k = k0 + col4 * 4;
            #pragma unroll
            for (int rr = 0; rr < 4; ++rr) {
                int nrow = rbase + rr * 32;
                const float4 v = *(const float4*)(Wl + (long)(n0 + nrow) * KDIM + k);
                short4 s;
                s.x = bf16rne(v.x); s.y = bf16rne(v.y);
                s.z = bf16rne(v.z); s.w = bf16rne(v.w);
                *(short4*)(&Bs[nrow * LDSTR + col4 * 4]) = s;
            }
        }
        __syncthreads();
        bf16x8 a[4], b[4];
        #pragma unroll
        for (int i = 0; i < 4; ++i)
            a[i] = *(const bf16x8*)(&As[(wm + i * 16 + lr) * LDSTR + wq * 8]);
        #pragma unroll
        for (int i = 0; i < 4; ++i)
            b[i] = *(const bf16x8*)(&Bs[(wn + i * 16 + lr) * LDSTR + wq * 8]);
        #pragma unroll
        for (int i = 0; i < 4; ++i)
            #pragma unroll
            for (int j = 0; j < 4; ++j)
                acc[i][j] = __builtin_amdgcn_mfma_f32_16x16x32_bf16(a[i], b[j], acc[i][j], 0, 0, 0);
        __syncthreads();
    }
    float bv[4];
    #pragma unroll
    for (int j = 0; j < 4; ++j) bv[j] = bias[n0 + wn + j * 16 + lr];
    #pragma unroll
    for (int i = 0; i < 4; ++i) {
        #pragma unroll
        for (int r = 0; r < 4; ++r) {
            int gm = m0 + wm + i * 16 + wq * 4 + r;
            if (gm < M) {
                int im = gm / NPATCH;
                int p  = gm % NPATCH;
                long orow = ((long)im * 197 + 1 + p) * (long)NDIM;
                #pragma unroll
                for (int j = 0; j < 4; ++j)
                    out[orow + n0 + wn + j * 16 + lr] = acc[i][j][r] + bv[j];
            }
        }
    }
}

__global__ __launch_bounds__(256) void cls_fill(
    const float* __restrict__ cls, float* __restrict__ out, int n_img)
{
    int i = blockIdx.x * 256 + threadIdx.x;
    if (i < n_img * NDIM) {
        int im = i / NDIM;
        int n  = i - im * NDIM;
        out[(long)im * 197 * NDIM + n] = cls[n];
    }
}

extern "C" void kernel_launch(void* const* d_in, const int* in_sizes, int n_in,
                              void* d_out, int out_size, void* d_ws, size_t ws_size,
                              hipStream_t stream) {
    const float* img  = (const float*)d_in[0];
    const float* Wl   = (const float*)d_in[1];
    const float* bias = (const float*)d_in[2];
    const float* cls  = (const float*)d_in[3];
    float* out = (float*)d_out;

    int n_img = in_sizes[0] / (CHN * IMGW * IMGW);
    int M = n_img * NPATCH;
    int mgroups = (M + 127) / 128;
    long Mpad = (long)mgroups * 128;

    size_t need = (size_t)(Mpad * KDIM + (long)KDIM * NDIM) * sizeof(short);
    if (ws_size >= need) {
        short* A_ws = (short*)d_ws;
        short* Wb   = A_ws + Mpad * KDIM;

        int total8 = n_img * (CHN * IMGW * IMGW / 8)   // image granules
                   + KDIM * NDIM / 8                   // W granules
                   + n_img * (NDIM / 8);               // cls granules
        prep_all<<<(total8 + 255) / 256, 256, 0, stream>>>(img, Wl, cls, A_ws, Wb, out, n_img);

        // XCD-swizzled 1-D grid: pad m-groups to multiple of 8
        int gpad = (mgroups + 7) & ~7;
        int nblocks = gpad * 6;
        vit_gemm3<<<nblocks, 256, 0, stream>>>(A_ws, Wb, bias, out, M, mgroups);
    } else {
        dim3 grid(NDIM / 128, mgroups);
        vit_gemm_fb<<<grid, 256, 0, stream>>>(img, Wl, bias, out, n_img);
        int cls_elems = n_img * NDIM;
        cls_fill<<<(cls_elems + 255) / 256, 256, 0, stream>>>(cls, out, n_img);
    }
}

// Round 3
// 174.841 us; speedup vs baseline: 1.1213x; 1.0244x over previous
//
#include <hip/hip_runtime.h>
#include <cstdint>

// ViT patch embedding, two-stage.
//   prep_all:  image-linear patchify+cvt -> bf16 A, W -> bf16 Wb, cls -> out.
//              (R2: near HBM floor, keep.)
//   vit_gemm3: R3 change — depth-2 register prefetch + double-buffered LDS.
//              R2 post-mortem: 2-barrier/K-step chain measured ~2800 cyc/step
//              vs ~460 cyc of work; loads issued mid-iter t are drained by the
//              ds_write at iter t+1 top (hiding window < latency). Now loads
//              for tile t+2 are issued at iter t and ds_written at iter t+1 —
//              a full iteration of hiding — and dbuf LDS cuts barriers 2->1
//              per K-step. Reg staging (not global_load_lds) keeps
//              __syncthreads vmcnt-free. Fragment mapping, XOR swizzle
//              (0 conflicts), XCD swizzle, epilogue: unchanged/verified.

#define PGRID 14
#define PSZ   16
#define CHN   3
#define IMGW  224
#define KDIM  768
#define NDIM  768
#define NPATCH 196

typedef short bf16x8 __attribute__((ext_vector_type(8)));
typedef short short8v __attribute__((ext_vector_type(8)));
typedef float f32x4  __attribute__((ext_vector_type(4)));

__device__ __forceinline__ short bf16rne(float f) {
    uint32_t u = __builtin_bit_cast(uint32_t, f);
    u += 0x7FFFu + ((u >> 16) & 1u);
    return (short)(u >> 16);
}

__device__ __forceinline__ short8v cvt8(float4 v0, float4 v1) {
    short8v s;
    s[0] = bf16rne(v0.x); s[1] = bf16rne(v0.y); s[2] = bf16rne(v0.z); s[3] = bf16rne(v0.w);
    s[4] = bf16rne(v1.x); s[5] = bf16rne(v1.y); s[6] = bf16rne(v1.z); s[7] = bf16rne(v1.w);
    return s;
}

// ---------------- prep: patchify + W convert + cls fill, image-linear ----------------
__global__ __launch_bounds__(256) void prep_all(
    const float* __restrict__ img, const float* __restrict__ Wl,
    const float* __restrict__ cls, short* __restrict__ A,
    short* __restrict__ Wb, float* __restrict__ out, int n_img)
{
    const int IMG8 = n_img * (CHN * IMGW * IMGW / 8);   // n*18816
    const int W8   = KDIM * NDIM / 8;                   // 73728
    int t = blockIdx.x * 256 + threadIdx.x;

    if (t < IMG8) {
        int w8    = t % (IMGW / 8);        // 0..27
        int rest  = t / (IMGW / 8);
        int h     = rest % IMGW;
        int rest2 = rest / IMGW;
        int c     = rest2 % CHN;
        int im    = rest2 / CHN;

        float4 v0 = *(const float4*)(img + (long)t * 8);
        float4 v1 = *(const float4*)(img + (long)t * 8 + 4);

        int Pi = h >> 4;
        int ph = h & 15;
        int Pj = w8 >> 1;
        int pw = (w8 & 1) * 8;
        int m  = im * NPATCH + Pi * PGRID + Pj;
        int k  = (c << 8) + (ph << 4) + pw;
        *(short8v*)(A + (long)m * KDIM + k) = cvt8(v0, v1);
    } else if (t < IMG8 + W8) {
        int u = t - IMG8;
        float4 v0 = *(const float4*)(Wl + (long)u * 8);
        float4 v1 = *(const float4*)(Wl + (long)u * 8 + 4);
        *(short8v*)(Wb + (long)u * 8) = cvt8(v0, v1);
    } else {
        int u = t - IMG8 - W8;
        if (u < n_img * (NDIM / 8)) {
            int im = u / (NDIM / 8);
            int k8 = u - im * (NDIM / 8);
            float4 v0 = *(const float4*)(cls + k8 * 8);
            float4 v1 = *(const float4*)(cls + k8 * 8 + 4);
            float* dst = out + (long)im * 197 * NDIM + k8 * 8;
            *(float4*)dst = v0;
            *(float4*)(dst + 4) = v1;
        }
    }
}

// ---------------- main GEMM: bf16 A[M][768] @ Wb[768][768]^T + bias ----------------
__global__ __launch_bounds__(256) void vit_gemm3(
    const short* __restrict__ A, const short* __restrict__ B,
    const float* __restrict__ bias, float* __restrict__ out,
    int M, int mgroups)
{
    // XCD-aware decode: 6 n-blocks of one m-group land on the same XCD
    const int bid = blockIdx.x;
    const int xcd = bid & 7;
    const int s   = bid >> 3;
    const int gq  = s / 6;
    const int j   = s - gq * 6;
    const int g   = gq * 8 + xcd;          // m-group
    if (g >= mgroups) return;
    const int m0 = g * 128;
    const int n0 = j * 128;

    // double-buffered, XOR-swizzled: (row, k16) at row*64 + ((k16^(row&7))*8)
    __shared__ short As0[128 * 64];   // 16 KB each, 64 KB total
    __shared__ short Bs0[128 * 64];
    __shared__ short As1[128 * 64];
    __shared__ short Bs1[128 * 64];

    const int tid = threadIdx.x;
    const int wave = tid >> 6;
    const int lane = tid & 63;

    // staging coords: slot b = jj*256 + tid; phys LDS offset = b*8 shorts;
    // logical row = jj*32 + (tid>>3); logical chunk = (tid&7) ^ (row&7)
    const int srow = tid >> 3;
    const int sk   = (tid & 7) ^ (srow & 7);
    const long abase = (long)(m0 + srow) * KDIM + sk * 8;
    const long bbase = (long)(n0 + srow) * KDIM + sk * 8;

    // compute coords
    const int wm = (wave & 1) * 64;
    const int wn = (wave >> 1) * 64;
    const int wq = lane >> 4;
    const int lr = lane & 15;
    const int blk0 = ((wq)     ^ (lr & 7)) * 8;
    const int blk1 = ((wq + 4) ^ (lr & 7)) * 8;

    f32x4 acc[4][4] = {};
    bf16x8 sa0[4], sb0[4], sa1[4], sb1[4];   // two named staging sets (static idx)

#define LOADT(SA, SB, KOFF)                                                  \
    {                                                                        \
        _Pragma("unroll")                                                    \
        for (int jj = 0; jj < 4; ++jj) {                                     \
            SA[jj] = *(const bf16x8*)(A + abase + (long)jj * 32 * KDIM + (KOFF)); \
            SB[jj] = *(const bf16x8*)(B + bbase + (long)jj * 32 * KDIM + (KOFF)); \
        }                                                                    \
    }

#define WRITET(AS, BS, SA, SB)                                               \
    {                                                                        \
        _Pragma("unroll")                                                    \
        for (int jj = 0; jj < 4; ++jj) {                                     \
            *(bf16x8*)(&AS[(jj * 256 + tid) * 8]) = SA[jj];                  \
            *(bf16x8*)(&BS[(jj * 256 + tid) * 8]) = SB[jj];                  \
        }                                                                    \
    }

#define COMPUTE(AS, BS)                                                      \
    {                                                                        \
        _Pragma("unroll")                                                    \
        for (int ks = 0; ks < 2; ++ks) {                                     \
            const int blk = ks ? blk1 : blk0;                                \
            bf16x8 a[4], b[4];                                               \
            _Pragma("unroll")                                                \
            for (int i = 0; i < 4; ++i)                                      \
                a[i] = *(const bf16x8*)(&AS[(wm + i * 16 + lr) * 64 + blk]); \
            _Pragma("unroll")                                                \
            for (int i = 0; i < 4; ++i)                                      \
                b[i] = *(const bf16x8*)(&BS[(wn + i * 16 + lr) * 64 + blk]); \
            _Pragma("unroll")                                                \
            for (int i = 0; i < 4; ++i)                                      \
                _Pragma("unroll")                                            \
                for (int jm = 0; jm < 4; ++jm)                               \
                    acc[i][jm] = __builtin_amdgcn_mfma_f32_16x16x32_bf16(    \
                        a[i], b[jm], acc[i][jm], 0, 0, 0);                   \
        }                                                                    \
    }

    // prologue: tiles 0 and 1 into the two register sets; tile 0 -> buf0
    LOADT(sa0, sb0, 0)
    LOADT(sa1, sb1, 64)
    WRITET(As0, Bs0, sa0, sb0)        // compiler vmcnt-waits set0 here (once)
    __syncthreads();

    // 12 K-steps, unrolled in pairs. Invariant at top of even iter t:
    //   buf[t&1] = tile t (ready), set1 = tile t+1 (in flight >=1 iter),
    //   set0 = free.
    #pragma unroll
    for (int u = 0; u < 6; ++u) {
        const int t = 2 * u;
        // ---- even iter: compute tile t from buf0
        if (t + 1 < 12) WRITET(As1, Bs1, sa1, sb1)       // tile t+1 -> buf1
        if (t + 2 < 12) LOADT(sa0, sb0, (t + 2) * 64)    // issue tile t+2
        COMPUTE(As0, Bs0)
        __syncthreads();
        // ---- odd iter: compute tile t+1 from buf1
        if (t + 2 < 12) WRITET(As0, Bs0, sa0, sb0)       // tile t+2 -> buf0
        if (t + 3 < 12) LOADT(sa1, sb1, (t + 3) * 64)    // issue tile t+3
        COMPUTE(As1, Bs1)
        __syncthreads();
    }

#undef LOADT
#undef WRITET
#undef COMPUTE

    float bv[4];
    #pragma unroll
    for (int jm = 0; jm < 4; ++jm) bv[jm] = bias[n0 + wn + jm * 16 + lr];

    #pragma unroll
    for (int i = 0; i < 4; ++i) {
        #pragma unroll
        for (int r = 0; r < 4; ++r) {
            int gm = m0 + wm + i * 16 + wq * 4 + r;
            if (gm < M) {
                int im = gm / NPATCH;
                int p  = gm - im * NPATCH;
                long orow = ((long)im * 197 + 1 + p) * (long)NDIM;
                #pragma unroll
                for (int jm = 0; jm < 4; ++jm)
                    out[orow + n0 + wn + jm * 16 + lr] = acc[i][jm][r] + bv[jm];
            }
        }
    }
}

// ---------------- fallback (no ws needed) ----------------
#define LDSTR 40
__global__ __launch_bounds__(256) void vit_gemm_fb(
    const float* __restrict__ img, const float* __restrict__ Wl,
    const float* __restrict__ bias, float* __restrict__ out, int n_img)
{
    const int M = n_img * NPATCH;
    __shared__ short As[128 * LDSTR];
    __shared__ short Bs[128 * LDSTR];
    const int tid = threadIdx.x;
    const int m0 = blockIdx.y * 128;
    const int n0 = blockIdx.x * 128;
    const int col4  = tid & 7;
    const int rbase = tid >> 3;
    long arow[4];
    for (int rr = 0; rr < 4; ++rr) {
        int m = m0 + rbase + rr * 32;
        int mm = (m < M) ? m : (M - 1);
        int im = mm / NPATCH;
        int p  = mm % NPATCH;
        int Pi = p / PGRID;
        int Pj = p % PGRID;
        arow[rr] = ((long)(im * CHN) * IMGW + Pi * PSZ) * IMGW + Pj * PSZ;
    }
    const int lane = tid & 63;
    const int wave = tid >> 6;
    const int wm = (wave & 1) * 64;
    const int wn = (wave >> 1) * 64;
    const int wq = lane >> 4;
    const int lr = lane & 15;
    f32x4 acc[4][4] = {};
    for (int k0 = 0; k0 < KDIM; k0 += 32) {
        {
            int k  = k0 + col4 * 4;
            int c  = k >> 8;
            int ph = (k >> 4) & 15;
            int pw = k & 15;
            long koff = (long)(c * IMGW + ph) * IMGW + pw;
            #pragma unroll
            for (int rr = 0; rr < 4; ++rr) {
                const float4 v = *(const float4*)(img + arow[rr] + koff);
                int row = rbase + rr * 32;
                short4 s;
                s.x = bf16rne(v.x); s.y = bf16rne(v.y);
                s.z = bf16rne(v.z); s.w = bf16rne(v.w);
                *(short4*)(&As[row * LDSTR + col4 * 4]) = s;
            }
        }
        {
            int k = k0 + col4 * 4;
            #pragma unroll
            for (int rr = 0; rr < 4; ++rr) {
                int nrow = rbase + rr * 32;
                const float4 v = *(const float4*)(Wl + (long)(n0 + nrow) * KDIM + k);
                short4 s;
                s.x = bf16rne(v.x); s.y = bf16rne(v.y);
                s.z = bf16rne(v.z); s.w = bf16rne(v.w);
                *(short4*)(&Bs[nrow * LDSTR + col4 * 4]) = s;
            }
        }
        __syncthreads();
        bf16x8 a[4], b[4];
        #pragma unroll
        for (int i = 0; i < 4; ++i)
            a[i] = *(const bf16x8*)(&As[(wm + i * 16 + lr) * LDSTR + wq * 8]);
        #pragma unroll
        for (int i = 0; i < 4; ++i)
            b[i] = *(const bf16x8*)(&Bs[(wn + i * 16 + lr) * LDSTR + wq * 8]);
        #pragma unroll
        for (int i = 0; i < 4; ++i)
            #pragma unroll
            for (int j = 0; j < 4; ++j)
                acc[i][j] = __builtin_amdgcn_mfma_f32_16x16x32_bf16(a[i], b[j], acc[i][j], 0, 0, 0);
        __syncthreads();
    }
    float bv[4];
    #pragma unroll
    for (int j = 0; j < 4; ++j) bv[j] = bias[n0 + wn + j * 16 + lr];
    #pragma unroll
    for (int i = 0; i < 4; ++i) {
        #pragma unroll
        for (int r = 0; r < 4; ++r) {
            int gm = m0 + wm + i * 16 + wq * 4 + r;
            if (gm < M) {
                int im = gm / NPATCH;
                int p  = gm % NPATCH;
                long orow = ((long)im * 197 + 1 + p) * (long)NDIM;
                #pragma unroll
                for (int j = 0; j < 4; ++j)
                    out[orow + n0 + wn + j * 16 + lr] = acc[i][j][r] + bv[j];
            }
        }
    }
}

__global__ __launch_bounds__(256) void cls_fill(
    const float* __restrict__ cls, float* __restrict__ out, int n_img)
{
    int i = blockIdx.x * 256 + threadIdx.x;
    if (i < n_img * NDIM) {
        int im = i / NDIM;
        int n  = i - im * NDIM;
        out[(long)im * 197 * NDIM + n] = cls[n];
    }
}

extern "C" void kernel_launch(void* const* d_in, const int* in_sizes, int n_in,
                              void* d_out, int out_size, void* d_ws, size_t ws_size,
                              hipStream_t stream) {
    const float* img  = (const float*)d_in[0];
    const float* Wl   = (const float*)d_in[1];
    const float* bias = (const float*)d_in[2];
    const float* cls  = (const float*)d_in[3];
    float* out = (float*)d_out;

    int n_img = in_sizes[0] / (CHN * IMGW * IMGW);
    int M = n_img * NPATCH;
    int mgroups = (M + 127) / 128;
    long Mpad = (long)mgroups * 128;

    size_t need = (size_t)(Mpad * KDIM + (long)KDIM * NDIM) * sizeof(short);
    if (ws_size >= need) {
        short* A_ws = (short*)d_ws;
        short* Wb   = A_ws + Mpad * KDIM;

        int total8 = n_img * (CHN * IMGW * IMGW / 8)
                   + KDIM * NDIM / 8
                   + n_img * (NDIM / 8);
        prep_all<<<(total8 + 255) / 256, 256, 0, stream>>>(img, Wl, cls, A_ws, Wb, out, n_img);

        // XCD-swizzled 1-D grid: pad m-groups to multiple of 8
        int gpad = (mgroups + 7) & ~7;
        int nblocks = gpad * 6;
        vit_gemm3<<<nblocks, 256, 0, stream>>>(A_ws, Wb, bias, out, M, mgroups);
    } else {
        dim3 grid(NDIM / 128, mgroups);
        vit_gemm_fb<<<grid, 256, 0, stream>>>(img, Wl, bias, out, n_img);
        int cls_elems = n_img * NDIM;
        cls_fill<<<(cls_elems + 255) / 256, 256, 0, stream>>>(cls, out, n_img);
    }
}

// Round 4
// 173.972 us; speedup vs baseline: 1.1269x; 1.0050x over previous
//
#include <hip/hip_runtime.h>
#include <cstdint>

// ViT patch embedding, two-stage.
//   prep_all:  image-linear patchify+cvt -> bf16 A, W -> bf16 Wb, cls -> out.
//              (R2: near HBM floor, keep.)
//   vit_gemm3: R4 change — depth-3 register prefetch (3 named staging sets)
//              + double-buffered LDS, 1 barrier/K-step.
//              R3 post-mortem: depth-2's hiding window (~1 COMPUTE ~600cy)
//              < first-touch HBM latency (~900cy); per-step stall ~3900cy vs
//              ~600cy work, MfmaUtil only 23%. Depth-3 gives loads 2 full
//              iterations + barriers (~2000cy) in flight before their
//              ds_write drains them. Swizzle (0 conflicts), fragment map,
//              XCD grid swizzle, epilogue: unchanged/verified.

#define PGRID 14
#define PSZ   16
#define CHN   3
#define IMGW  224
#define KDIM  768
#define NDIM  768
#define NPATCH 196

typedef short bf16x8 __attribute__((ext_vector_type(8)));
typedef short short8v __attribute__((ext_vector_type(8)));
typedef float f32x4  __attribute__((ext_vector_type(4)));

__device__ __forceinline__ short bf16rne(float f) {
    uint32_t u = __builtin_bit_cast(uint32_t, f);
    u += 0x7FFFu + ((u >> 16) & 1u);
    return (short)(u >> 16);
}

__device__ __forceinline__ short8v cvt8(float4 v0, float4 v1) {
    short8v s;
    s[0] = bf16rne(v0.x); s[1] = bf16rne(v0.y); s[2] = bf16rne(v0.z); s[3] = bf16rne(v0.w);
    s[4] = bf16rne(v1.x); s[5] = bf16rne(v1.y); s[6] = bf16rne(v1.z); s[7] = bf16rne(v1.w);
    return s;
}

// ---------------- prep: patchify + W convert + cls fill, image-linear ----------------
__global__ __launch_bounds__(256) void prep_all(
    const float* __restrict__ img, const float* __restrict__ Wl,
    const float* __restrict__ cls, short* __restrict__ A,
    short* __restrict__ Wb, float* __restrict__ out, int n_img)
{
    const int IMG8 = n_img * (CHN * IMGW * IMGW / 8);   // n*18816
    const int W8   = KDIM * NDIM / 8;                   // 73728
    int t = blockIdx.x * 256 + threadIdx.x;

    if (t < IMG8) {
        int w8    = t % (IMGW / 8);        // 0..27
        int rest  = t / (IMGW / 8);
        int h     = rest % IMGW;
        int rest2 = rest / IMGW;
        int c     = rest2 % CHN;
        int im    = rest2 / CHN;

        float4 v0 = *(const float4*)(img + (long)t * 8);
        float4 v1 = *(const float4*)(img + (long)t * 8 + 4);

        int Pi = h >> 4;
        int ph = h & 15;
        int Pj = w8 >> 1;
        int pw = (w8 & 1) * 8;
        int m  = im * NPATCH + Pi * PGRID + Pj;
        int k  = (c << 8) + (ph << 4) + pw;
        *(short8v*)(A + (long)m * KDIM + k) = cvt8(v0, v1);
    } else if (t < IMG8 + W8) {
        int u = t - IMG8;
        float4 v0 = *(const float4*)(Wl + (long)u * 8);
        float4 v1 = *(const float4*)(Wl + (long)u * 8 + 4);
        *(short8v*)(Wb + (long)u * 8) = cvt8(v0, v1);
    } else {
        int u = t - IMG8 - W8;
        if (u < n_img * (NDIM / 8)) {
            int im = u / (NDIM / 8);
            int k8 = u - im * (NDIM / 8);
            float4 v0 = *(const float4*)(cls + k8 * 8);
            float4 v1 = *(const float4*)(cls + k8 * 8 + 4);
            float* dst = out + (long)im * 197 * NDIM + k8 * 8;
            *(float4*)dst = v0;
            *(float4*)(dst + 4) = v1;
        }
    }
}

// ---------------- main GEMM: bf16 A[M][768] @ Wb[768][768]^T + bias ----------------
__global__ __launch_bounds__(256) void vit_gemm3(
    const short* __restrict__ A, const short* __restrict__ B,
    const float* __restrict__ bias, float* __restrict__ out,
    int M, int mgroups)
{
    // XCD-aware decode: 6 n-blocks of one m-group land on the same XCD
    const int bid = blockIdx.x;
    const int xcd = bid & 7;
    const int s   = bid >> 3;
    const int gq  = s / 6;
    const int j   = s - gq * 6;
    const int g   = gq * 8 + xcd;          // m-group
    if (g >= mgroups) return;
    const int m0 = g * 128;
    const int n0 = j * 128;

    // double-buffered, XOR-swizzled: (row, k16) at row*64 + ((k16^(row&7))*8)
    __shared__ short As0[128 * 64];   // 16 KB each, 64 KB total
    __shared__ short Bs0[128 * 64];
    __shared__ short As1[128 * 64];
    __shared__ short Bs1[128 * 64];

    const int tid = threadIdx.x;
    const int wave = tid >> 6;
    const int lane = tid & 63;

    // staging coords: slot b = jj*256 + tid; phys LDS offset = b*8 shorts;
    // logical row = jj*32 + (tid>>3); logical chunk = (tid&7) ^ (row&7)
    const int srow = tid >> 3;
    const int sk   = (tid & 7) ^ (srow & 7);
    const long abase = (long)(m0 + srow) * KDIM + sk * 8;
    const long bbase = (long)(n0 + srow) * KDIM + sk * 8;

    // compute coords
    const int wm = (wave & 1) * 64;
    const int wn = (wave >> 1) * 64;
    const int wq = lane >> 4;
    const int lr = lane & 15;
    const int blk0 = ((wq)     ^ (lr & 7)) * 8;
    const int blk1 = ((wq + 4) ^ (lr & 7)) * 8;

    f32x4 acc[4][4] = {};
    // three named staging sets (static indexing, rule #20)
    bf16x8 sa0[4], sb0[4], sa1[4], sb1[4], sa2[4], sb2[4];

#define LOADT(SA, SB, KOFF)                                                  \
    {                                                                        \
        _Pragma("unroll")                                                    \
        for (int jj = 0; jj < 4; ++jj) {                                     \
            SA[jj] = *(const bf16x8*)(A + abase + (long)jj * 32 * KDIM + (KOFF)); \
            SB[jj] = *(const bf16x8*)(B + bbase + (long)jj * 32 * KDIM + (KOFF)); \
        }                                                                    \
    }

#define WRITET(AS, BS, SA, SB)                                               \
    {                                                                        \
        _Pragma("unroll")                                                    \
        for (int jj = 0; jj < 4; ++jj) {                                     \
            *(bf16x8*)(&AS[(jj * 256 + tid) * 8]) = SA[jj];                  \
            *(bf16x8*)(&BS[(jj * 256 + tid) * 8]) = SB[jj];                  \
        }                                                                    \
    }

#define COMPUTE(AS, BS)                                                      \
    {                                                                        \
        _Pragma("unroll")                                                    \
        for (int ks = 0; ks < 2; ++ks) {                                     \
            const int blk = ks ? blk1 : blk0;                                \
            bf16x8 a[4], b[4];                                               \
            _Pragma("unroll")                                                \
            for (int i = 0; i < 4; ++i)                                      \
                a[i] = *(const bf16x8*)(&AS[(wm + i * 16 + lr) * 64 + blk]); \
            _Pragma("unroll")                                                \
            for (int i = 0; i < 4; ++i)                                      \
                b[i] = *(const bf16x8*)(&BS[(wn + i * 16 + lr) * 64 + blk]); \
            _Pragma("unroll")                                                \
            for (int i = 0; i < 4; ++i)                                      \
                _Pragma("unroll")                                            \
                for (int jm = 0; jm < 4; ++jm)                               \
                    acc[i][jm] = __builtin_amdgcn_mfma_f32_16x16x32_bf16(    \
                        a[i], b[jm], acc[i][jm], 0, 0, 0);                   \
        }                                                                    \
    }

    // prologue: tiles 0..2 in flight; tile 0 -> buf0
    LOADT(sa0, sb0, 0)
    LOADT(sa1, sb1, 64)
    LOADT(sa2, sb2, 128)
    WRITET(As0, Bs0, sa0, sb0)        // waits only tile-0 loads (vmcnt(16))
    __syncthreads();

    // 12 K-steps, depth-3. Invariant at top of step t:
    //   buf[t&1]    = tile t   (ready)
    //   set[(t+1)%3]= tile t+1 (in flight >=2 iters)
    //   set[(t+2)%3]= tile t+2 (in flight >=1 iter)
    //   set[t%3]    = free (ds_written at t-1)
    // Step t: WRITE tile t+1 -> buf[(t+1)&1]; ISSUE tile t+3 -> set[t%3];
    //         COMPUTE buf[t&1]; barrier.
#define STEP(WA, WB, WSA, WSB, LSA, LSB, KOFF, CA, CB, DO_L, DO_B)           \
    WRITET(WA, WB, WSA, WSB)                                                 \
    if (DO_L) LOADT(LSA, LSB, KOFF)                                          \
    COMPUTE(CA, CB)                                                          \
    if (DO_B) __syncthreads();

    STEP(As1, Bs1, sa1, sb1, sa0, sb0, 192, As0, Bs0, 1, 1)  // t=0
    STEP(As0, Bs0, sa2, sb2, sa1, sb1, 256, As1, Bs1, 1, 1)  // t=1
    STEP(As1, Bs1, sa0, sb0, sa2, sb2, 320, As0, Bs0, 1, 1)  // t=2
    STEP(As0, Bs0, sa1, sb1, sa0, sb0, 384, As1, Bs1, 1, 1)  // t=3
    STEP(As1, Bs1, sa2, sb2, sa1, sb1, 448, As0, Bs0, 1, 1)  // t=4
    STEP(As0, Bs0, sa0, sb0, sa2, sb2, 512, As1, Bs1, 1, 1)  // t=5
    STEP(As1, Bs1, sa1, sb1, sa0, sb0, 576, As0, Bs0, 1, 1)  // t=6
    STEP(As0, Bs0, sa2, sb2, sa1, sb1, 640, As1, Bs1, 1, 1)  // t=7
    STEP(As1, Bs1, sa0, sb0, sa2, sb2, 704, As0, Bs0, 1, 1)  // t=8
    STEP(As0, Bs0, sa1, sb1, sa1, sb1,   0, As1, Bs1, 0, 1)  // t=9  (no load)
    STEP(As1, Bs1, sa2, sb2, sa1, sb1,   0, As0, Bs0, 0, 1)  // t=10 (no load)
    COMPUTE(As1, Bs1)                                         // t=11 (no write/barrier)

#undef STEP
#undef LOADT
#undef WRITET
#undef COMPUTE

    float bv[4];
    #pragma unroll
    for (int jm = 0; jm < 4; ++jm) bv[jm] = bias[n0 + wn + jm * 16 + lr];

    #pragma unroll
    for (int i = 0; i < 4; ++i) {
        #pragma unroll
        for (int r = 0; r < 4; ++r) {
            int gm = m0 + wm + i * 16 + wq * 4 + r;
            if (gm < M) {
                int im = gm / NPATCH;
                int p  = gm - im * NPATCH;
                long orow = ((long)im * 197 + 1 + p) * (long)NDIM;
                #pragma unroll
                for (int jm = 0; jm < 4; ++jm)
                    out[orow + n0 + wn + jm * 16 + lr] = acc[i][jm][r] + bv[jm];
            }
        }
    }
}

// ---------------- fallback (no ws needed) ----------------
#define LDSTR 40
__global__ __launch_bounds__(256) void vit_gemm_fb(
    const float* __restrict__ img, const float* __restrict__ Wl,
    const float* __restrict__ bias, float* __restrict__ out, int n_img)
{
    const int M = n_img * NPATCH;
    __shared__ short As[128 * LDSTR];
    __shared__ short Bs[128 * LDSTR];
    const int tid = threadIdx.x;
    const int m0 = blockIdx.y * 128;
    const int n0 = blockIdx.x * 128;
    const int col4  = tid & 7;
    const int rbase = tid >> 3;
    long arow[4];
    for (int rr = 0; rr < 4; ++rr) {
        int m = m0 + rbase + rr * 32;
        int mm = (m < M) ? m : (M - 1);
        int im = mm / NPATCH;
        int p  = mm % NPATCH;
        int Pi = p / PGRID;
        int Pj = p % PGRID;
        arow[rr] = ((long)(im * CHN) * IMGW + Pi * PSZ) * IMGW + Pj * PSZ;
    }
    const int lane = tid & 63;
    const int wave = tid >> 6;
    const int wm = (wave & 1) * 64;
    const int wn = (wave >> 1) * 64;
    const int wq = lane >> 4;
    const int lr = lane & 15;
    f32x4 acc[4][4] = {};
    for (int k0 = 0; k0 < KDIM; k0 += 32) {
        {
            int k  = k0 + col4 * 4;
            int c  = k >> 8;
            int ph = (k >> 4) & 15;
            int pw = k & 15;
            long koff = (long)(c * IMGW + ph) * IMGW + pw;
            #pragma unroll
            for (int rr = 0; rr < 4; ++rr) {
                const float4 v = *(const float4*)(img + arow[rr] + koff);
                int row = rbase + rr * 32;
                short4 s;
                s.x = bf16rne(v.x); s.y = bf16rne(v.y);
                s.z = bf16rne(v.z); s.w = bf16rne(v.w);
                *(short4*)(&As[row * LDSTR + col4 * 4]) = s;
            }
        }
        {
            int k = k0 + col4 * 4;
            #pragma unroll
            for (int rr = 0; rr < 4; ++rr) {
                int nrow = rbase + rr * 32;
                const float4 v = *(const float4*)(Wl + (long)(n0 + nrow) * KDIM + k);
                short4 s;
                s.x = bf16rne(v.x); s.y = bf16rne(v.y);
                s.z = bf16rne(v.z); s.w = bf16rne(v.w);
                *(short4*)(&Bs[nrow * LDSTR + col4 * 4]) = s;
            }
        }
        __syncthreads();
        bf16x8 a[4], b[4];
        #pragma unroll
        for (int i = 0; i < 4; ++i)
            a[i] = *(const bf16x8*)(&As[(wm + i * 16 + lr) * LDSTR + wq * 8]);
        #pragma unroll
        for (int i = 0; i < 4; ++i)
            b[i] = *(const bf16x8*)(&Bs[(wn + i * 16 + lr) * LDSTR + wq * 8]);
        #pragma unroll
        for (int i = 0; i < 4; ++i)
            #pragma unroll
            for (int j = 0; j < 4; ++j)
                acc[i][j] = __builtin_amdgcn_mfma_f32_16x16x32_bf16(a[i], b[j], acc[i][j], 0, 0, 0);
        __syncthreads();
    }
    float bv[4];
    #pragma unroll
    for (int j = 0; j < 4; ++j) bv[j] = bias[n0 + wn + j * 16 + lr];
    #pragma unroll
    for (int i = 0; i < 4; ++i) {
        #pragma unroll
        for (int r = 0; r < 4; ++r) {
            int gm = m0 + wm + i * 16 + wq * 4 + r;
            if (gm < M) {
                int im = gm / NPATCH;
                int p  = gm % NPATCH;
                long orow = ((long)im * 197 + 1 + p) * (long)NDIM;
                #pragma unroll
                for (int j = 0; j < 4; ++j)
                    out[orow + n0 + wn + j * 16 + lr] = acc[i][j][r] + bv[j];
            }
        }
    }
}

__global__ __launch_bounds__(256) void cls_fill(
    const float* __restrict__ cls, float* __restrict__ out, int n_img)
{
    int i = blockIdx.x * 256 + threadIdx.x;
    if (i < n_img * NDIM) {
        int im = i / NDIM;
        int n  = i - im * NDIM;
        out[(long)im * 197 * NDIM + n] = cls[n];
    }
}

extern "C" void kernel_launch(void* const* d_in, const int* in_sizes, int n_in,
                              void* d_out, int out_size, void* d_ws, size_t ws_size,
                              hipStream_t stream) {
    const float* img  = (const float*)d_in[0];
    const float* Wl   = (const float*)d_in[1];
    const float* bias = (const float*)d_in[2];
    const float* cls  = (const float*)d_in[3];
    float* out = (float*)d_out;

    int n_img = in_sizes[0] / (CHN * IMGW * IMGW);
    int M = n_img * NPATCH;
    int mgroups = (M + 127) / 128;
    long Mpad = (long)mgroups * 128;

    size_t need = (size_t)(Mpad * KDIM + (long)KDIM * NDIM) * sizeof(short);
    if (ws_size >= need) {
        short* A_ws = (short*)d_ws;
        short* Wb   = A_ws + Mpad * KDIM;

        int total8 = n_img * (CHN * IMGW * IMGW / 8)
                   + KDIM * NDIM / 8
                   + n_img * (NDIM / 8);
        prep_all<<<(total8 + 255) / 256, 256, 0, stream>>>(img, Wl, cls, A_ws, Wb, out, n_img);

        // XCD-swizzled 1-D grid: pad m-groups to multiple of 8
        int gpad = (mgroups + 7) & ~7;
        int nblocks = gpad * 6;
        vit_gemm3<<<nblocks, 256, 0, stream>>>(A_ws, Wb, bias, out, M, mgroups);
    } else {
        dim3 grid(NDIM / 128, mgroups);
        vit_gemm_fb<<<grid, 256, 0, stream>>>(img, Wl, bias, out, n_img);
        int cls_elems = n_img * NDIM;
        cls_fill<<<(cls_elems + 255) / 256, 256, 0, stream>>>(cls, out, n_img);
    }
}